// Round 12
// baseline (127.722 us; speedup 1.0000x reference)
//
#include <hip/hip_runtime.h>
#include <stdint.h>

#define S_ 512
#define B_ 32
#define D_ 256
#define XSZ ((int64_t)B_ * S_ * D_)

typedef __attribute__((ext_vector_type(8))) short bf16x8;
typedef __attribute__((ext_vector_type(4))) float f32x4;
typedef long long i64;

#define WAITVM(n) asm volatile("s_waitcnt vmcnt(" #n ")" ::: "memory")
#define WAITLG() asm volatile("s_waitcnt lgkmcnt(0)" ::: "memory")
#define SCHEDB() __builtin_amdgcn_sched_barrier(0)
#define BAR() __builtin_amdgcn_s_barrier()

__device__ __forceinline__ unsigned short f2bf(float f) {
    union { float f; uint32_t u; } v; v.f = f;
    uint32_t r = v.u + 0x7FFFu + ((v.u >> 16) & 1u);
    return (unsigned short)(r >> 16);
}
__device__ __forceinline__ float bf2f(unsigned short h) {
    union { uint32_t u; float f; } v; v.u = ((uint32_t)h) << 16;
    return v.f;
}
__device__ __forceinline__ uint32_t pk2(float a, float b) {
    return (uint32_t)f2bf(a) | ((uint32_t)f2bf(b) << 16);
}

// f32 -> fp8 e4m3fn, RNE. Inputs here are always |f| < 256 (no saturation path).
__device__ __forceinline__ uint32_t f2f8(float f) {
    union { float f; uint32_t u; } v; v.f = f;
    const uint32_t s = (v.u >> 24) & 0x80u;
    const int e = (int)((v.u >> 23) & 0xFF) - 127;
    const uint32_t m = v.u & 0x7FFFFFu;
    if (e >= -6) {                       // normal e4m3
        uint32_t mant = m >> 20;
        uint32_t rest = m & 0xFFFFFu;
        mant += (rest > 0x80000u) || (rest == 0x80000u && (mant & 1u));
        uint32_t exp = (uint32_t)(e + 7);
        if (mant == 8u) { mant = 0u; exp++; }
        return s | (exp << 3) | mant;
    }
    if (e < -10) return s;               // flush tiny to 0
    uint32_t full = 0x800000u | m;       // subnormal target: mant * 2^-9
    const int shift = 14 - e;
    uint32_t mant = full >> shift;
    uint32_t rem = full & ((1u << shift) - 1u);
    uint32_t half = 1u << (shift - 1);
    mant += (rem > half) || (rem == half && (mant & 1u));
    if (mant >= 8u) return s | (1u << 3);
    return s | mant;
}
__device__ __forceinline__ uint32_t pk4f8(float a, float b, float c, float d) {
    return f2f8(a) | (f2f8(b) << 8) | (f2f8(c) << 16) | (f2f8(d) << 24);
}

__device__ __forceinline__ void gl_lds16(const void* g, void* lds_base) {
    __builtin_amdgcn_global_load_lds(
        (const __attribute__((address_space(1))) unsigned int*)g,
        (__attribute__((address_space(3))) unsigned int*)lds_base, 16, 0, 0);
}

__device__ __forceinline__ f32x4 MF(bf16x8 a, bf16x8 b, f32x4 c) {
    return __builtin_amdgcn_mfma_f32_16x16x32_bf16(a, b, c, 0, 0, 0);
}
__device__ __forceinline__ f32x4 MF8(i64 a, i64 b, f32x4 c) {
    return __builtin_amdgcn_mfma_f32_16x16x32_fp8_fp8(a, b, c, 0, 0, 0);
}

// ---------- fused prep: [0,12288) adj->fp8  [12288,13312) xT->fp8  [13312,13696) W ----------
__global__ __launch_bounds__(256) void prep_kernel(
    const float* __restrict__ adj, const float* __restrict__ gcn,
    const float* __restrict__ W, const float* __restrict__ Wout,
    unsigned char* __restrict__ adjF8, float* __restrict__ dInv,
    unsigned char* __restrict__ Xf8T,
    unsigned short* __restrict__ Wbf, unsigned char* __restrict__ Wout8)
{
    __shared__ unsigned short T[64 * 65];
    const int bx = blockIdx.x;
    const int tid = threadIdx.x;

    if (bx < 12288) {  // ---- adj: fp8 + I, dInv (rowsum from f32) ----
        const int flat = bx * 4 + (tid >> 6);
        const int lane = tid & 63;
        const float* src = adj + (int64_t)flat * S_ + lane * 8;
        float4 v0 = ((const float4*)src)[0];
        float4 v1 = ((const float4*)src)[1];
        float sum = v0.x + v0.y + v0.z + v0.w + v1.x + v1.y + v1.z + v1.w;
#pragma unroll
        for (int o = 1; o < 64; o <<= 1) sum += __shfl_xor(sum, o);
        const int s = flat & (S_ - 1);
        const int c0 = lane * 8;
        float e0 = v0.x + ((s == c0 + 0) ? 1.f : 0.f);
        float e1 = v0.y + ((s == c0 + 1) ? 1.f : 0.f);
        float e2 = v0.z + ((s == c0 + 2) ? 1.f : 0.f);
        float e3 = v0.w + ((s == c0 + 3) ? 1.f : 0.f);
        float e4 = v1.x + ((s == c0 + 4) ? 1.f : 0.f);
        float e5 = v1.y + ((s == c0 + 5) ? 1.f : 0.f);
        float e6 = v1.z + ((s == c0 + 6) ? 1.f : 0.f);
        float e7 = v1.w + ((s == c0 + 7) ? 1.f : 0.f);
        uint2 p;
        p.x = pk4f8(e0, e1, e2, e3);
        p.y = pk4f8(e4, e5, e6, e7);
        *(uint2*)&adjF8[(int64_t)flat * S_ + c0] = p;
        if (lane == 0) dInv[flat] = 1.0f / (sum + 1.0f);
    } else if (bx < 13312) {  // ---- gcn -> Xf8T (transpose, fp8) ----
        const int idx = bx - 12288;
        const int s0 = (idx & 7) * 64, d0 = ((idx >> 3) & 3) * 64, b = idx >> 5;
        const int r = tid >> 2, seg = tid & 3;
        const float* src = gcn + ((int64_t)(b * S_ + s0 + r)) * D_ + d0 + seg * 16;
#pragma unroll
        for (int q = 0; q < 4; q++) {
            float4 v = ((const float4*)src)[q];
            unsigned short* t = &T[r * 65 + seg * 16 + q * 4];
            t[0] = f2bf(v.x); t[1] = f2bf(v.y); t[2] = f2bf(v.z); t[3] = f2bf(v.w);
        }
        __syncthreads();
        uint32_t q8[4];
#pragma unroll
        for (int j = 0; j < 4; j++) {
            float a = bf2f(T[(seg * 16 + j * 4 + 0) * 65 + r]);
            float b2 = bf2f(T[(seg * 16 + j * 4 + 1) * 65 + r]);
            float c = bf2f(T[(seg * 16 + j * 4 + 2) * 65 + r]);
            float d = bf2f(T[(seg * 16 + j * 4 + 3) * 65 + r]);
            q8[j] = pk4f8(a, b2, c, d);
        }
        *(uint4*)&Xf8T[((int64_t)(b * D_ + d0 + r)) * S_ + s0 + seg * 16] = *(uint4*)q8;
    } else {  // ---- W -> bf16 (mm2), Wout -> fp8 (final) ----
        const int i = ((bx - 13312) * 256 + tid) * 4;
        {
            float4 v = *(const float4*)&W[i];
            uint2 p; p.x = pk2(v.x, v.y); p.y = pk2(v.z, v.w);
            *(uint2*)&Wbf[i] = p;
        }
        {
            float4 v = *(const float4*)&Wout[i];
            *(uint32_t*)&Wout8[i] = pk4f8(v.x, v.y, v.z, v.w);
        }
    }
}

// ---------- layers: 768 blocks @ 3/CU, 4 waves, tile 64s x 256d ----------
// bmm FP8 BK=128 x4; bufA dbuf cross-wave; bufB wave-private issue-early.
// mm2 bf16 as R11. y stored FP8 (for final), yT8 fp8 (for L1).
template<int L>
__global__ __launch_bounds__(256, 3) void layers_kernel(
    const unsigned char* __restrict__ adjF8,   // [3][B][S][S] fp8 (diag+1)
    const unsigned char* __restrict__ Xf8T,    // [B][D][S] fp8    (L==0 input)
    unsigned char* __restrict__ yT8,           // [3][B][D][S] fp8 (L==0 out / L==1 in)
    const unsigned short* __restrict__ Wbf,    // [6][D][D] bf16
    const float* __restrict__ bvec,            // [6][D]
    const float* __restrict__ dInv,            // [3][B][S]
    unsigned char* __restrict__ y8All)         // [6][B][S][D] fp8
{
    __shared__ __align__(16) char smem[50176];

    const int tid = threadIdx.x;
    const int w   = tid >> 6;
    const int l   = tid & 63;
    const int lm  = l & 15;
    const int g   = l >> 4;

    int flat = blockIdx.x;
    flat = (flat & 7) * 96 + (flat >> 3);      // XCD-chunked (768 = 8*96, bijective)
    const int h  = flat >> 8;
    const int rem = flat & 255;
    const int b  = rem >> 3;
    const int s0 = (rem & 7) * 64;

    const unsigned char* adjB = adjF8 + (((int64_t)h * B_ + b) * S_ + s0) * S_;
    const unsigned char* xTB  = (L == 0) ? (Xf8T + (int64_t)b * D_ * S_)
                                         : (yT8 + ((int64_t)h * B_ + b) * D_ * S_);
    const unsigned short* Wl  = Wbf + (int64_t)(h * 2 + L) * D_ * D_;
    const float* bl           = bvec + (h * 2 + L) * D_;
    const float* dInvB        = dInv + ((int64_t)h * B_ + b) * S_ + s0;

    const int srow8 = l >> 3;
    const int sch16 = ((l & 7) ^ (l >> 3)) * 16;

    f32x4 acc[4][4];
#pragma unroll
    for (int i = 0; i < 4; i++)
#pragma unroll
        for (int j = 0; j < 4; j++) acc[i][j] = (f32x4){0.f, 0.f, 0.f, 0.f};

    auto stageA = [&](int t0, int cur) {         // 2 gl_lds per wave
        char* bA = smem + cur * 8192;
        gl_lds16(&adjB[(w * 16 + srow8) * S_ + t0 + sch16], bA + w * 2048);
        gl_lds16(&adjB[(w * 16 + 8 + srow8) * S_ + t0 + sch16], bA + w * 2048 + 1024);
    };
    auto stageB = [&](int t0) {                  // 8 gl_lds into OWN slice
        char* bB = smem + 16384 + w * 8192;
#pragma unroll
        for (int j = 0; j < 8; j++)
            gl_lds16(&xTB[(int64_t)(w * 64 + j * 8 + srow8) * S_ + t0 + sch16],
                     bB + j * 1024);
    };

    // ---- bmm (fp8): P = (A+I)x, 4 steps of BK=128, issue-early B restage ----
    stageA(0, 0);
    stageB(0);
    for (int t = 0; t < 4; t++) {
        const int cur = t & 1;
        if (t < 3) { stageA((t + 1) * 128, cur ^ 1); WAITVM(2); }
        else       { WAITVM(0); }
        SCHEDB(); BAR(); SCHEDB();
        {
            const char* bA = smem + cur * 8192;
            const char* bB = smem + 16384 + w * 8192;
            i64 bF2[4][4];
#pragma unroll
            for (int kk = 0; kk < 4; kk++) {
                const int co8 = (((kk * 2 + (g >> 1)) ^ (lm & 7)) << 4) + ((g & 1) << 3);
#pragma unroll
                for (int ni = 0; ni < 4; ni++)
                    bF2[kk][ni] = *(const i64*)(bB + (ni * 16 + lm) * 128 + co8);
            }
            WAITLG(); SCHEDB();
            if (t < 3) stageB((t + 1) * 128);
            SCHEDB();
            __builtin_amdgcn_s_setprio(1);
#pragma unroll
            for (int kk = 0; kk < 4; kk++) {
                const int co8 = (((kk * 2 + (g >> 1)) ^ (lm & 7)) << 4) + ((g & 1) << 3);
                i64 aF[4];
#pragma unroll
                for (int mi = 0; mi < 4; mi++)
                    aF[mi] = *(const i64*)(bA + (mi * 16 + lm) * 128 + co8);
#pragma unroll
                for (int ni = 0; ni < 4; ni++)
#pragma unroll
                    for (int mi = 0; mi < 4; mi++)
                        acc[mi][ni] = MF8(aF[mi], bF2[kk][ni], acc[mi][ni]);
            }
            __builtin_amdgcn_s_setprio(0);
        }
        SCHEDB(); BAR();
    }

    // ---- P -> Ps (bf16, stride 264) ----
    unsigned short* Ps = (unsigned short*)smem;
#pragma unroll
    for (int mi = 0; mi < 4; mi++)
#pragma unroll
        for (int ni = 0; ni < 4; ni++) {
            const int col = w * 64 + ni * 16 + lm;
#pragma unroll
            for (int r = 0; r < 4; r++)
                Ps[(mi * 16 + g * 4 + r) * 264 + col] = f2bf(acc[mi][ni][r]);
        }

    const int sr16 = l >> 2;
    const int sc4  = ((l & 3) ^ ((l >> 3) & 3)) * 8;
    auto stageW = [&](int kc) {                  // 4 gl_lds into OWN slice
        char* bW = smem + 33792 + w * 4096;
#pragma unroll
        for (int j = 0; j < 4; j++)
            gl_lds16(&Wl[(w * 64 + j * 16 + sr16) * D_ + kc * 32 + sc4],
                     bW + j * 1024);
    };
    stageW(0);
    __syncthreads();

    // ---- mm2: Q = P @ W^T, 8 steps of BK=32, barrier-free, issue-early W ----
    f32x4 acc2[4][4];
#pragma unroll
    for (int i = 0; i < 4; i++)
#pragma unroll
        for (int j = 0; j < 4; j++) acc2[i][j] = (f32x4){0.f, 0.f, 0.f, 0.f};

    for (int kc = 0; kc < 8; kc++) {
        WAITVM(0);
        SCHEDB();
        {
            const char* bW = smem + 33792 + w * 4096;
            const int co2 = (g ^ ((lm >> 1) & 3)) << 4;
            bf16x8 bF[4];
#pragma unroll
            for (int ni = 0; ni < 4; ni++)
                bF[ni] = *(const bf16x8*)(bW + (ni * 16 + lm) * 64 + co2);
            WAITLG(); SCHEDB();
            if (kc < 7) stageW(kc + 1);
            SCHEDB();
            bf16x8 aF[4];
#pragma unroll
            for (int mi = 0; mi < 4; mi++)
                aF[mi] = *(const bf16x8*)&Ps[(mi * 16 + lm) * 264 + kc * 32 + g * 8];
            __builtin_amdgcn_s_setprio(1);
#pragma unroll
            for (int ni = 0; ni < 4; ni++)
#pragma unroll
                for (int mi = 0; mi < 4; mi++)
                    acc2[mi][ni] = MF(aF[mi], bF[ni], acc2[mi][ni]);
            __builtin_amdgcn_s_setprio(0);
        }
    }
    __syncthreads();

    // ---- epilogue: y = relu((Q + 2b) * dInv) -> Ps ----
    float dv[4][4];
#pragma unroll
    for (int mi = 0; mi < 4; mi++)
#pragma unroll
        for (int r = 0; r < 4; r++)
            dv[mi][r] = dInvB[mi * 16 + g * 4 + r];

#pragma unroll
    for (int ni = 0; ni < 4; ni++) {
        const int col = w * 64 + ni * 16 + lm;
        const float bv = 2.0f * bl[col];
#pragma unroll
        for (int mi = 0; mi < 4; mi++)
#pragma unroll
            for (int r = 0; r < 4; r++) {
                float v = (acc2[mi][ni][r] + bv) * dv[mi][r];
                v = v > 0.f ? v : 0.f;
                Ps[(mi * 16 + g * 4 + r) * 264 + col] = f2bf(v);
            }
    }
    __syncthreads();

    // fp8 y store (row-major, for final): thread = (row rr, quarter seg), 64B
    {
        unsigned char* y8 = y8All + (int64_t)(h * 2 + L) * XSZ + (int64_t)(b * S_ + s0) * D_;
        const int rr = tid >> 2, seg = (tid & 3) * 64;
        uint32_t tmp[16];
#pragma unroll
        for (int q = 0; q < 16; q++) {
            float a = bf2f(Ps[rr * 264 + seg + q * 4 + 0]);
            float b2 = bf2f(Ps[rr * 264 + seg + q * 4 + 1]);
            float c = bf2f(Ps[rr * 264 + seg + q * 4 + 2]);
            float d = bf2f(Ps[rr * 264 + seg + q * 4 + 3]);
            tmp[q] = pk4f8(a, b2, c, d);
        }
        uint4* dst = (uint4*)&y8[rr * D_ + seg];
#pragma unroll
        for (int q = 0; q < 4; q++) dst[q] = ((uint4*)tmp)[q];
    }
    if (L == 0) {  // transposed fp8 yT for L1's bmm B-operand
        unsigned char* yT = yT8 + ((int64_t)h * B_ + b) * D_ * S_;
        const int e = tid;
        uint32_t tmp[16];
#pragma unroll
        for (int sq = 0; sq < 16; sq++) {
            float a = bf2f(Ps[(sq * 4 + 0) * 264 + e]);
            float b2 = bf2f(Ps[(sq * 4 + 1) * 264 + e]);
            float c = bf2f(Ps[(sq * 4 + 2) * 264 + e]);
            float d = bf2f(Ps[(sq * 4 + 3) * 264 + e]);
            tmp[sq] = pk4f8(a, b2, c, d);
        }
        uint4* dst = (uint4*)&yT[(int64_t)e * S_ + s0];
#pragma unroll
        for (int q = 0; q < 4; q++) dst[q] = ((uint4*)tmp)[q];
    }
}

// ---------- final (fp8): 512 blocks @ 4/CU, 32s x 256e, BK=128 x12 steps ----------
__global__ __launch_bounds__(256, 4) void final_kernel(
    const unsigned char* __restrict__ y8All,   // [6][B][S][D] fp8
    const unsigned char* __restrict__ Wout8,   // [256][1536] fp8
    const float* __restrict__ gcn,
    const float* __restrict__ bout,
    float* __restrict__ out)
{
    __shared__ __align__(16) char smem[40960];
    // bufA dbuf [0,8192) (2 x 32rows x 128B); bufB slice w: [8192 + w*8192, +8192)

    const int tid = threadIdx.x;
    const int w   = tid >> 6;
    const int l   = tid & 63;
    const int lm  = l & 15;
    const int g   = l >> 4;

    int flat = blockIdx.x;
    flat = (flat & 7) * 64 + (flat >> 3);    // 512 = 8*64, bijective
    const int b  = flat >> 4;
    const int s0 = (flat & 15) * 32;

    const int srow8 = l >> 3;
    const int sch16 = ((l & 7) ^ (l >> 3)) * 16;
    const unsigned char* yBase = y8All + (int64_t)(b * S_ + s0) * D_;

    auto stageA = [&](int kc, int cur) {      // 1 gl_lds per wave
        char* bA = smem + cur * 4096;
        const int hl = kc >> 1;
        const int e0 = (kc & 1) * 128;
        gl_lds16(&yBase[(int64_t)hl * XSZ + (w * 8 + srow8) * D_ + e0 + sch16],
                 bA + w * 1024);
    };
    auto stageB = [&](int kc) {               // 8 gl_lds into OWN slice
        char* bB = smem + 8192 + w * 8192;
#pragma unroll
        for (int j = 0; j < 8; j++)
            gl_lds16(&Wout8[(w * 64 + j * 8 + srow8) * 1536 + kc * 128 + sch16],
                     bB + j * 1024);
    };

    f32x4 acc[2][4];
#pragma unroll
    for (int i = 0; i < 2; i++)
#pragma unroll
        for (int j = 0; j < 4; j++) acc[i][j] = (f32x4){0.f, 0.f, 0.f, 0.f};

    stageA(0, 0);
    stageB(0);
    for (int t = 0; t < 12; t++) {
        const int cur = t & 1;
        if (t < 11) { stageA(t + 1, cur ^ 1); WAITVM(1); }
        else        { WAITVM(0); }
        SCHEDB(); BAR(); SCHEDB();
        {
            const char* bA = smem + cur * 4096;
            const char* bB = smem + 8192 + w * 8192;
            i64 bF2[4][4];
#pragma unroll
            for (int kk = 0; kk < 4; kk++) {
                const int co8 = (((kk * 2 + (g >> 1)) ^ (lm & 7)) << 4) + ((g & 1) << 3);
#pragma unroll
                for (int ni = 0; ni < 4; ni++)
                    bF2[kk][ni] = *(const i64*)(bB + (ni * 16 + lm) * 128 + co8);
            }
            WAITLG(); SCHEDB();
            if (t < 11) stageB(t + 1);
            SCHEDB();
            __builtin_amdgcn_s_setprio(1);
#pragma unroll
            for (int kk = 0; kk < 4; kk++) {
                const int co8 = (((kk * 2 + (g >> 1)) ^ (lm & 7)) << 4) + ((g & 1) << 3);
                i64 a0 = *(const i64*)(bA + lm * 128 + co8);
                i64 a1 = *(const i64*)(bA + (16 + lm) * 128 + co8);
#pragma unroll
                for (int ni = 0; ni < 4; ni++) {
                    acc[0][ni] = MF8(a0, bF2[kk][ni], acc[0][ni]);
                    acc[1][ni] = MF8(a1, bF2[kk][ni], acc[1][ni]);
                }
            }
            __builtin_amdgcn_s_setprio(0);
        }
        SCHEDB(); BAR();
    }

#pragma unroll
    for (int ni = 0; ni < 4; ni++) {
        const int e = w * 64 + ni * 16 + lm;
        const float bo = bout[e];
#pragma unroll
        for (int mi = 0; mi < 2; mi++)
#pragma unroll
            for (int r = 0; r < 4; r++) {
                const int row = mi * 16 + g * 4 + r;
                const int64_t idx = ((int64_t)(b * S_ + s0 + row)) * D_ + e;
                out[idx] = acc[mi][ni][r] + gcn[idx] + bo;
            }
    }
}

extern "C" void kernel_launch(void* const* d_in, const int* in_sizes, int n_in,
                              void* d_out, int out_size, void* d_ws, size_t ws_size,
                              hipStream_t stream) {
    const float* adj  = (const float*)d_in[0];
    const float* gcn  = (const float*)d_in[1];
    const float* W    = (const float*)d_in[4];
    const float* bvec = (const float*)d_in[5];
    const float* Wout = (const float*)d_in[6];
    const float* bout = (const float*)d_in[7];
    float* out = (float*)d_out;

    const int64_t ADJ_N = (int64_t)3 * B_ * S_ * S_;   // fp8 bytes
    unsigned char* adjF8  = (unsigned char*)d_ws;
    unsigned char* Xf8T   = adjF8 + ADJ_N;             // B*D*S bytes
    unsigned char* yT8    = Xf8T + XSZ;                // 3*B*D*S bytes
    unsigned char* y8All  = yT8 + 3 * XSZ;             // 6*B*S*D bytes
    unsigned short* Wbf   = (unsigned short*)(y8All + 6 * XSZ);
    unsigned char* Wout8  = (unsigned char*)(Wbf + 6 * D_ * D_);
    float* dInv           = (float*)(Wout8 + 6 * D_ * D_);      // [3][B][S]

    prep_kernel<<<13696, 256, 0, stream>>>(adj, gcn, W, Wout,
                                           adjF8, dInv, Xf8T, Wbf, Wout8);
    layers_kernel<0><<<768, 256, 0, stream>>>(adjF8, Xf8T, yT8, Wbf, bvec, dInv, y8All);
    layers_kernel<1><<<768, 256, 0, stream>>>(adjF8, Xf8T, yT8, Wbf, bvec, dInv, y8All);
    final_kernel<<<512, 256, 0, stream>>>(y8All, Wout8, gcn, bout, out);
}

// Round 13
// 95.719 us; speedup vs baseline: 1.3343x; 1.3343x over previous
//
#include <hip/hip_runtime.h>
#include <stdint.h>

#define S_ 512
#define B_ 32
#define D_ 256
#define XSZ ((int64_t)B_ * S_ * D_)

typedef __attribute__((ext_vector_type(8))) short bf16x8;
typedef __attribute__((ext_vector_type(4))) float f32x4;
typedef long long i64;

#define WAITVM(n) asm volatile("s_waitcnt vmcnt(" #n ")" ::: "memory")
#define WAITLG() asm volatile("s_waitcnt lgkmcnt(0)" ::: "memory")
#define SCHEDB() __builtin_amdgcn_sched_barrier(0)
#define BAR() __builtin_amdgcn_s_barrier()

__device__ __forceinline__ unsigned short f2bf(float f) {
    union { float f; uint32_t u; } v; v.f = f;
    uint32_t r = v.u + 0x7FFFu + ((v.u >> 16) & 1u);
    return (unsigned short)(r >> 16);
}
__device__ __forceinline__ float bf2f(unsigned short h) {
    union { uint32_t u; float f; } v; v.u = ((uint32_t)h) << 16;
    return v.f;
}
__device__ __forceinline__ uint32_t pk2(float a, float b) {
    return (uint32_t)f2bf(a) | ((uint32_t)f2bf(b) << 16);
}

// f32x4 -> 4x fp8 e4m3 via HW converter (RNE, OCP on gfx950): 2 instructions.
__device__ __forceinline__ uint32_t pk4f8(float a, float b, float c, float d) {
    int r = __builtin_amdgcn_cvt_pk_fp8_f32(a, b, 0, false);   // low 16 bits
    r = __builtin_amdgcn_cvt_pk_fp8_f32(c, d, r, true);        // high 16 bits
    return (uint32_t)r;
}

__device__ __forceinline__ void gl_lds16(const void* g, void* lds_base) {
    __builtin_amdgcn_global_load_lds(
        (const __attribute__((address_space(1))) unsigned int*)g,
        (__attribute__((address_space(3))) unsigned int*)lds_base, 16, 0, 0);
}

__device__ __forceinline__ f32x4 MF(bf16x8 a, bf16x8 b, f32x4 c) {
    return __builtin_amdgcn_mfma_f32_16x16x32_bf16(a, b, c, 0, 0, 0);
}
__device__ __forceinline__ f32x4 MF8(i64 a, i64 b, f32x4 c) {
    return __builtin_amdgcn_mfma_f32_16x16x32_fp8_fp8(a, b, c, 0, 0, 0);
}

// ---------- fused prep: [0,12288) adj->fp8  [12288,13312) xT->fp8  [13312,13696) W ----------
__global__ __launch_bounds__(256) void prep_kernel(
    const float* __restrict__ adj, const float* __restrict__ gcn,
    const float* __restrict__ W, const float* __restrict__ Wout,
    unsigned char* __restrict__ adjF8, float* __restrict__ dInv,
    unsigned char* __restrict__ Xf8T,
    unsigned short* __restrict__ Wbf, unsigned char* __restrict__ Wout8)
{
    __shared__ unsigned short T[64 * 65];
    const int bx = blockIdx.x;
    const int tid = threadIdx.x;

    if (bx < 12288) {  // ---- adj: fp8 + I, dInv (rowsum from f32) ----
        const int flat = bx * 4 + (tid >> 6);
        const int lane = tid & 63;
        const float* src = adj + (int64_t)flat * S_ + lane * 8;
        float4 v0 = ((const float4*)src)[0];
        float4 v1 = ((const float4*)src)[1];
        float sum = v0.x + v0.y + v0.z + v0.w + v1.x + v1.y + v1.z + v1.w;
#pragma unroll
        for (int o = 1; o < 64; o <<= 1) sum += __shfl_xor(sum, o);
        const int s = flat & (S_ - 1);
        const int c0 = lane * 8;
        float e0 = v0.x + ((s == c0 + 0) ? 1.f : 0.f);
        float e1 = v0.y + ((s == c0 + 1) ? 1.f : 0.f);
        float e2 = v0.z + ((s == c0 + 2) ? 1.f : 0.f);
        float e3 = v0.w + ((s == c0 + 3) ? 1.f : 0.f);
        float e4 = v1.x + ((s == c0 + 4) ? 1.f : 0.f);
        float e5 = v1.y + ((s == c0 + 5) ? 1.f : 0.f);
        float e6 = v1.z + ((s == c0 + 6) ? 1.f : 0.f);
        float e7 = v1.w + ((s == c0 + 7) ? 1.f : 0.f);
        uint2 p;
        p.x = pk4f8(e0, e1, e2, e3);
        p.y = pk4f8(e4, e5, e6, e7);
        *(uint2*)&adjF8[(int64_t)flat * S_ + c0] = p;
        if (lane == 0) dInv[flat] = 1.0f / (sum + 1.0f);
    } else if (bx < 13312) {  // ---- gcn -> Xf8T (transpose, fp8) ----
        const int idx = bx - 12288;
        const int s0 = (idx & 7) * 64, d0 = ((idx >> 3) & 3) * 64, b = idx >> 5;
        const int r = tid >> 2, seg = tid & 3;
        const float* src = gcn + ((int64_t)(b * S_ + s0 + r)) * D_ + d0 + seg * 16;
#pragma unroll
        for (int q = 0; q < 4; q++) {
            float4 v = ((const float4*)src)[q];
            unsigned short* t = &T[r * 65 + seg * 16 + q * 4];
            t[0] = f2bf(v.x); t[1] = f2bf(v.y); t[2] = f2bf(v.z); t[3] = f2bf(v.w);
        }
        __syncthreads();
        uint32_t q8[4];
#pragma unroll
        for (int j = 0; j < 4; j++) {
            float a = bf2f(T[(seg * 16 + j * 4 + 0) * 65 + r]);
            float b2 = bf2f(T[(seg * 16 + j * 4 + 1) * 65 + r]);
            float c = bf2f(T[(seg * 16 + j * 4 + 2) * 65 + r]);
            float d = bf2f(T[(seg * 16 + j * 4 + 3) * 65 + r]);
            q8[j] = pk4f8(a, b2, c, d);
        }
        *(uint4*)&Xf8T[((int64_t)(b * D_ + d0 + r)) * S_ + s0 + seg * 16] = *(uint4*)q8;
    } else {  // ---- W -> bf16 (mm2), Wout -> fp8 (final) ----
        const int i = ((bx - 13312) * 256 + tid) * 4;
        {
            float4 v = *(const float4*)&W[i];
            uint2 p; p.x = pk2(v.x, v.y); p.y = pk2(v.z, v.w);
            *(uint2*)&Wbf[i] = p;
        }
        {
            float4 v = *(const float4*)&Wout[i];
            *(uint32_t*)&Wout8[i] = pk4f8(v.x, v.y, v.z, v.w);
        }
    }
}

// ---------- layers: 768 blocks @ 3/CU, 4 waves, tile 64s x 256d ----------
// bmm FP8 BK=128 x4; bufA dbuf cross-wave; bufB wave-private issue-early.
// mm2 bf16. y stored FP8 (for final), yT8 fp8 (for L1). HW cvt for all fp8 packs.
template<int L>
__global__ __launch_bounds__(256, 3) void layers_kernel(
    const unsigned char* __restrict__ adjF8,   // [3][B][S][S] fp8 (diag+1)
    const unsigned char* __restrict__ Xf8T,    // [B][D][S] fp8    (L==0 input)
    unsigned char* __restrict__ yT8,           // [3][B][D][S] fp8 (L==0 out / L==1 in)
    const unsigned short* __restrict__ Wbf,    // [6][D][D] bf16
    const float* __restrict__ bvec,            // [6][D]
    const float* __restrict__ dInv,            // [3][B][S]
    unsigned char* __restrict__ y8All)         // [6][B][S][D] fp8
{
    __shared__ __align__(16) char smem[50176];

    const int tid = threadIdx.x;
    const int w   = tid >> 6;
    const int l   = tid & 63;
    const int lm  = l & 15;
    const int g   = l >> 4;

    int flat = blockIdx.x;
    flat = (flat & 7) * 96 + (flat >> 3);      // XCD-chunked (768 = 8*96, bijective)
    const int h  = flat >> 8;
    const int rem = flat & 255;
    const int b  = rem >> 3;
    const int s0 = (rem & 7) * 64;

    const unsigned char* adjB = adjF8 + (((int64_t)h * B_ + b) * S_ + s0) * S_;
    const unsigned char* xTB  = (L == 0) ? (Xf8T + (int64_t)b * D_ * S_)
                                         : (yT8 + ((int64_t)h * B_ + b) * D_ * S_);
    const unsigned short* Wl  = Wbf + (int64_t)(h * 2 + L) * D_ * D_;
    const float* bl           = bvec + (h * 2 + L) * D_;
    const float* dInvB        = dInv + ((int64_t)h * B_ + b) * S_ + s0;

    const int srow8 = l >> 3;
    const int sch16 = ((l & 7) ^ (l >> 3)) * 16;

    f32x4 acc[4][4];
#pragma unroll
    for (int i = 0; i < 4; i++)
#pragma unroll
        for (int j = 0; j < 4; j++) acc[i][j] = (f32x4){0.f, 0.f, 0.f, 0.f};

    auto stageA = [&](int t0, int cur) {         // 2 gl_lds per wave
        char* bA = smem + cur * 8192;
        gl_lds16(&adjB[(w * 16 + srow8) * S_ + t0 + sch16], bA + w * 2048);
        gl_lds16(&adjB[(w * 16 + 8 + srow8) * S_ + t0 + sch16], bA + w * 2048 + 1024);
    };
    auto stageB = [&](int t0) {                  // 8 gl_lds into OWN slice
        char* bB = smem + 16384 + w * 8192;
#pragma unroll
        for (int j = 0; j < 8; j++)
            gl_lds16(&xTB[(int64_t)(w * 64 + j * 8 + srow8) * S_ + t0 + sch16],
                     bB + j * 1024);
    };

    // ---- bmm (fp8): P = (A+I)x, 4 steps of BK=128, issue-early B restage ----
    stageA(0, 0);
    stageB(0);
    for (int t = 0; t < 4; t++) {
        const int cur = t & 1;
        if (t < 3) { stageA((t + 1) * 128, cur ^ 1); WAITVM(2); }
        else       { WAITVM(0); }
        SCHEDB(); BAR(); SCHEDB();
        {
            const char* bA = smem + cur * 8192;
            const char* bB = smem + 16384 + w * 8192;
            i64 bF2[4][4];
#pragma unroll
            for (int kk = 0; kk < 4; kk++) {
                const int co8 = (((kk * 2 + (g >> 1)) ^ (lm & 7)) << 4) + ((g & 1) << 3);
#pragma unroll
                for (int ni = 0; ni < 4; ni++)
                    bF2[kk][ni] = *(const i64*)(bB + (ni * 16 + lm) * 128 + co8);
            }
            WAITLG(); SCHEDB();
            if (t < 3) stageB((t + 1) * 128);
            SCHEDB();
            __builtin_amdgcn_s_setprio(1);
#pragma unroll
            for (int kk = 0; kk < 4; kk++) {
                const int co8 = (((kk * 2 + (g >> 1)) ^ (lm & 7)) << 4) + ((g & 1) << 3);
                i64 aF[4];
#pragma unroll
                for (int mi = 0; mi < 4; mi++)
                    aF[mi] = *(const i64*)(bA + (mi * 16 + lm) * 128 + co8);
#pragma unroll
                for (int ni = 0; ni < 4; ni++)
#pragma unroll
                    for (int mi = 0; mi < 4; mi++)
                        acc[mi][ni] = MF8(aF[mi], bF2[kk][ni], acc[mi][ni]);
            }
            __builtin_amdgcn_s_setprio(0);
        }
        SCHEDB(); BAR();
    }

    // ---- P -> Ps (bf16, stride 264) ----
    unsigned short* Ps = (unsigned short*)smem;
#pragma unroll
    for (int mi = 0; mi < 4; mi++)
#pragma unroll
        for (int ni = 0; ni < 4; ni++) {
            const int col = w * 64 + ni * 16 + lm;
#pragma unroll
            for (int r = 0; r < 4; r++)
                Ps[(mi * 16 + g * 4 + r) * 264 + col] = f2bf(acc[mi][ni][r]);
        }

    const int sr16 = l >> 2;
    const int sc4  = ((l & 3) ^ ((l >> 3) & 3)) * 8;
    auto stageW = [&](int kc) {                  // 4 gl_lds into OWN slice
        char* bW = smem + 33792 + w * 4096;
#pragma unroll
        for (int j = 0; j < 4; j++)
            gl_lds16(&Wl[(w * 64 + j * 16 + sr16) * D_ + kc * 32 + sc4],
                     bW + j * 1024);
    };
    stageW(0);
    __syncthreads();

    // ---- mm2: Q = P @ W^T, 8 steps of BK=32, barrier-free, issue-early W ----
    f32x4 acc2[4][4];
#pragma unroll
    for (int i = 0; i < 4; i++)
#pragma unroll
        for (int j = 0; j < 4; j++) acc2[i][j] = (f32x4){0.f, 0.f, 0.f, 0.f};

    for (int kc = 0; kc < 8; kc++) {
        WAITVM(0);
        SCHEDB();
        {
            const char* bW = smem + 33792 + w * 4096;
            const int co2 = (g ^ ((lm >> 1) & 3)) << 4;
            bf16x8 bF[4];
#pragma unroll
            for (int ni = 0; ni < 4; ni++)
                bF[ni] = *(const bf16x8*)(bW + (ni * 16 + lm) * 64 + co2);
            WAITLG(); SCHEDB();
            if (kc < 7) stageW(kc + 1);
            SCHEDB();
            bf16x8 aF[4];
#pragma unroll
            for (int mi = 0; mi < 4; mi++)
                aF[mi] = *(const bf16x8*)&Ps[(mi * 16 + lm) * 264 + kc * 32 + g * 8];
            __builtin_amdgcn_s_setprio(1);
#pragma unroll
            for (int ni = 0; ni < 4; ni++)
#pragma unroll
                for (int mi = 0; mi < 4; mi++)
                    acc2[mi][ni] = MF(aF[mi], bF[ni], acc2[mi][ni]);
            __builtin_amdgcn_s_setprio(0);
        }
    }
    __syncthreads();

    // ---- epilogue: y = relu((Q + 2b) * dInv) -> Ps ----
    float dv[4][4];
#pragma unroll
    for (int mi = 0; mi < 4; mi++)
#pragma unroll
        for (int r = 0; r < 4; r++)
            dv[mi][r] = dInvB[mi * 16 + g * 4 + r];

#pragma unroll
    for (int ni = 0; ni < 4; ni++) {
        const int col = w * 64 + ni * 16 + lm;
        const float bv = 2.0f * bl[col];
#pragma unroll
        for (int mi = 0; mi < 4; mi++)
#pragma unroll
            for (int r = 0; r < 4; r++) {
                float v = (acc2[mi][ni][r] + bv) * dv[mi][r];
                v = v > 0.f ? v : 0.f;
                Ps[(mi * 16 + g * 4 + r) * 264 + col] = f2bf(v);
            }
    }
    __syncthreads();

    // fp8 y store (row-major, for final): thread = (row rr, quarter seg), 64B (HW cvt)
    {
        unsigned char* y8 = y8All + (int64_t)(h * 2 + L) * XSZ + (int64_t)(b * S_ + s0) * D_;
        const int rr = tid >> 2, seg = (tid & 3) * 64;
        uint32_t tmp[16];
#pragma unroll
        for (int q = 0; q < 16; q++) {
            float a = bf2f(Ps[rr * 264 + seg + q * 4 + 0]);
            float b2 = bf2f(Ps[rr * 264 + seg + q * 4 + 1]);
            float c = bf2f(Ps[rr * 264 + seg + q * 4 + 2]);
            float d = bf2f(Ps[rr * 264 + seg + q * 4 + 3]);
            tmp[q] = pk4f8(a, b2, c, d);
        }
        uint4* dst = (uint4*)&y8[rr * D_ + seg];
#pragma unroll
        for (int q = 0; q < 4; q++) dst[q] = ((uint4*)tmp)[q];
    }
    if (L == 0) {  // transposed fp8 yT for L1's bmm B-operand (HW cvt)
        unsigned char* yT = yT8 + ((int64_t)h * B_ + b) * D_ * S_;
        const int e = tid;
        uint32_t tmp[16];
#pragma unroll
        for (int sq = 0; sq < 16; sq++) {
            float a = bf2f(Ps[(sq * 4 + 0) * 264 + e]);
            float b2 = bf2f(Ps[(sq * 4 + 1) * 264 + e]);
            float c = bf2f(Ps[(sq * 4 + 2) * 264 + e]);
            float d = bf2f(Ps[(sq * 4 + 3) * 264 + e]);
            tmp[sq] = pk4f8(a, b2, c, d);
        }
        uint4* dst = (uint4*)&yT[(int64_t)e * S_ + s0];
#pragma unroll
        for (int q = 0; q < 4; q++) dst[q] = ((uint4*)tmp)[q];
    }
}

// ---------- final (fp8): 512 blocks @ 4/CU, 32s x 256e, BK=128 x12 steps ----------
__global__ __launch_bounds__(256, 4) void final_kernel(
    const unsigned char* __restrict__ y8All,   // [6][B][S][D] fp8
    const unsigned char* __restrict__ Wout8,   // [256][1536] fp8
    const float* __restrict__ gcn,
    const float* __restrict__ bout,
    float* __restrict__ out)
{
    __shared__ __align__(16) char smem[40960];
    // bufA dbuf [0,8192) (2 x 32rows x 128B); bufB slice w: [8192 + w*8192, +8192)

    const int tid = threadIdx.x;
    const int w   = tid >> 6;
    const int l   = tid & 63;
    const int lm  = l & 15;
    const int g   = l >> 4;

    int flat = blockIdx.x;
    flat = (flat & 7) * 64 + (flat >> 3);    // 512 = 8*64, bijective
    const int b  = flat >> 4;
    const int s0 = (flat & 15) * 32;

    const int srow8 = l >> 3;
    const int sch16 = ((l & 7) ^ (l >> 3)) * 16;
    const unsigned char* yBase = y8All + (int64_t)(b * S_ + s0) * D_;

    auto stageA = [&](int kc, int cur) {      // 1 gl_lds per wave
        char* bA = smem + cur * 4096;
        const int hl = kc >> 1;
        const int e0 = (kc & 1) * 128;
        gl_lds16(&yBase[(int64_t)hl * XSZ + (w * 8 + srow8) * D_ + e0 + sch16],
                 bA + w * 1024);
    };
    auto stageB = [&](int kc) {               // 8 gl_lds into OWN slice
        char* bB = smem + 8192 + w * 8192;
#pragma unroll
        for (int j = 0; j < 8; j++)
            gl_lds16(&Wout8[(w * 64 + j * 8 + srow8) * 1536 + kc * 128 + sch16],
                     bB + j * 1024);
    };

    f32x4 acc[2][4];
#pragma unroll
    for (int i = 0; i < 2; i++)
#pragma unroll
        for (int j = 0; j < 4; j++) acc[i][j] = (f32x4){0.f, 0.f, 0.f, 0.f};

    stageA(0, 0);
    stageB(0);
    for (int t = 0; t < 12; t++) {
        const int cur = t & 1;
        if (t < 11) { stageA(t + 1, cur ^ 1); WAITVM(1); }
        else        { WAITVM(0); }
        SCHEDB(); BAR(); SCHEDB();
        {
            const char* bA = smem + cur * 4096;
            const char* bB = smem + 8192 + w * 8192;
            i64 bF2[4][4];
#pragma unroll
            for (int kk = 0; kk < 4; kk++) {
                const int co8 = (((kk * 2 + (g >> 1)) ^ (lm & 7)) << 4) + ((g & 1) << 3);
#pragma unroll
                for (int ni = 0; ni < 4; ni++)
                    bF2[kk][ni] = *(const i64*)(bB + (ni * 16 + lm) * 128 + co8);
            }
            WAITLG(); SCHEDB();
            if (t < 11) stageB(t + 1);
            SCHEDB();
            __builtin_amdgcn_s_setprio(1);
#pragma unroll
            for (int kk = 0; kk < 4; kk++) {
                const int co8 = (((kk * 2 + (g >> 1)) ^ (lm & 7)) << 4) + ((g & 1) << 3);
                i64 a0 = *(const i64*)(bA + lm * 128 + co8);
                i64 a1 = *(const i64*)(bA + (16 + lm) * 128 + co8);
#pragma unroll
                for (int ni = 0; ni < 4; ni++) {
                    acc[0][ni] = MF8(a0, bF2[kk][ni], acc[0][ni]);
                    acc[1][ni] = MF8(a1, bF2[kk][ni], acc[1][ni]);
                }
            }
            __builtin_amdgcn_s_setprio(0);
        }
        SCHEDB(); BAR();
    }

#pragma unroll
    for (int ni = 0; ni < 4; ni++) {
        const int e = w * 64 + ni * 16 + lm;
        const float bo = bout[e];
#pragma unroll
        for (int mi = 0; mi < 2; mi++)
#pragma unroll
            for (int r = 0; r < 4; r++) {
                const int row = mi * 16 + g * 4 + r;
                const int64_t idx = ((int64_t)(b * S_ + s0 + row)) * D_ + e;
                out[idx] = acc[mi][ni][r] + gcn[idx] + bo;
            }
    }
}

extern "C" void kernel_launch(void* const* d_in, const int* in_sizes, int n_in,
                              void* d_out, int out_size, void* d_ws, size_t ws_size,
                              hipStream_t stream) {
    const float* adj  = (const float*)d_in[0];
    const float* gcn  = (const float*)d_in[1];
    const float* W    = (const float*)d_in[4];
    const float* bvec = (const float*)d_in[5];
    const float* Wout = (const float*)d_in[6];
    const float* bout = (const float*)d_in[7];
    float* out = (float*)d_out;

    const int64_t ADJ_N = (int64_t)3 * B_ * S_ * S_;   // fp8 bytes
    unsigned char* adjF8  = (unsigned char*)d_ws;
    unsigned char* Xf8T   = adjF8 + ADJ_N;             // B*D*S bytes
    unsigned char* yT8    = Xf8T + XSZ;                // 3*B*D*S bytes
    unsigned char* y8All  = yT8 + 3 * XSZ;             // 6*B*S*D bytes
    unsigned short* Wbf   = (unsigned short*)(y8All + 6 * XSZ);
    unsigned char* Wout8  = (unsigned char*)(Wbf + 6 * D_ * D_);
    float* dInv           = (float*)(Wout8 + 6 * D_ * D_);      // [3][B][S]

    prep_kernel<<<13696, 256, 0, stream>>>(adj, gcn, W, Wout,
                                           adjF8, dInv, Xf8T, Wbf, Wout8);
    layers_kernel<0><<<768, 256, 0, stream>>>(adjF8, Xf8T, yT8, Wbf, bvec, dInv, y8All);
    layers_kernel<1><<<768, 256, 0, stream>>>(adjF8, Xf8T, yT8, Wbf, bvec, dInv, y8All);
    final_kernel<<<512, 256, 0, stream>>>(y8All, Wout8, gcn, bout, out);
}